// Round 2
// baseline (129.819 us; speedup 1.0000x reference)
//
#include <hip/hip_runtime.h>
#include <hip/hip_bf16.h>

#define TASKS 16
#define DIM 1024
#define HID 128
#define NCLS 10
#define NB 65536
#define BM 128
#define NTILES (NB / BM + TASKS) // 528

typedef __attribute__((ext_vector_type(8))) short bf16x8;
typedef __attribute__((ext_vector_type(4))) float f32x4;

__device__ __forceinline__ short f2bf(float f) {
    __hip_bfloat16 h = __float2bfloat16(f);   // RNE, compiler pairs into v_cvt_pk_bf16_f32
    union { __hip_bfloat16 h; short s; } u; u.h = h; return u.s;
}

__device__ __forceinline__ bf16x8 pack8(f32x4 a, f32x4 b) {
    bf16x8 r;
    r[0]=f2bf(a[0]); r[1]=f2bf(a[1]); r[2]=f2bf(a[2]); r[3]=f2bf(a[3]);
    r[4]=f2bf(b[0]); r[5]=f2bf(b[1]); r[6]=f2bf(b[2]); r[7]=f2bf(b[3]);
    return r;
}

// ---- pass 1: histogram of task ids ----
__global__ __launch_bounds__(256) void k_hist(const int* __restrict__ tid_arr,
                                              int* __restrict__ cnt) {
    __shared__ int l[TASKS];
    int tx = threadIdx.x;
    if (tx < TASKS) l[tx] = 0;
    __syncthreads();
    int t = tid_arr[blockIdx.x * 256 + tx];
    atomicAdd(&l[t], 1);
    __syncthreads();
    if (tx < TASKS) atomicAdd(&cnt[tx], l[tx]);
}

// ---- pass 2: tiny serial scan ----
__global__ void k_scan(int* __restrict__ ws) {
    if (threadIdx.x == 0 && blockIdx.x == 0) {
        int* cnt = ws; int* off = ws + 16; int* tb = ws + 33; int* cur = ws + 50;
        int ro = 0, rt = 0;
        for (int t = 0; t < TASKS; ++t) {
            off[t] = ro; cur[t] = ro; tb[t] = rt;
            ro += cnt[t]; rt += (cnt[t] + BM - 1) / BM;
        }
        off[TASKS] = ro; tb[TASKS] = rt;
    }
}

// ---- pass 3: scatter row indices grouped by task ----
__global__ __launch_bounds__(256) void k_scatter(const int* __restrict__ tid_arr,
                                                 int* __restrict__ ws) {
    __shared__ int l[TASKS], base[TASKS];
    int* cur = ws + 50;
    int* rowIdx = ws + 256;
    int tx = threadIdx.x;
    if (tx < TASKS) l[tx] = 0;
    __syncthreads();
    int i = blockIdx.x * 256 + tx;
    int t = tid_arr[i];
    int rank = atomicAdd(&l[t], 1);
    __syncthreads();
    if (tx < TASKS) base[tx] = atomicAdd(&cur[tx], l[tx]);
    __syncthreads();
    rowIdx[base[t] + rank] = i;
}

// ---- pass 4: fused grouped GEMM: relu(x*W1[t]+b1[t])*W2[t]+b2[t] ----
// BK=64, double-buffered, 1 barrier/iter, XOR-swizzled 128B LDS rows.
__global__ __launch_bounds__(256, 2) void k_main(
    const float* __restrict__ x, const float* __restrict__ W1,
    const float* __restrict__ b1, const float* __restrict__ W2,
    const float* __restrict__ b2, const int* __restrict__ ws,
    float* __restrict__ out)
{
    // stage: buf b: A at smem + b*16384 (8192 shorts), B at +8192. 64KB total.
    // epilogue (reuse): hlds [128][128] at 0 (16384 shorts), w2lds [16][128] at 16384.
    __shared__ __align__(16) short smem[32768];
    __shared__ int ridx[BM];

    const int* cnt = ws; const int* off = ws + 16; const int* tb = ws + 33;
    const int* rowIdx = ws + 256;

    const int w = blockIdx.x;
    if (w >= tb[TASKS]) return;
    int t = 0;
    #pragma unroll
    for (int i = 1; i < TASKS; ++i) if (w >= tb[i]) t = i;
    const int tileInT = w - tb[t];
    const int gstart = off[t] + tileInT * BM;
    int m = cnt[t] - tileInT * BM; if (m > BM) m = BM;

    const int tid = threadIdx.x;
    if (tid < BM) {
        int rr = tid < m ? tid : (m - 1);   // clamp: partial tiles duplicate last row
        ridx[tid] = rowIdx[gstart + rr];
    }
    __syncthreads();

    const int lane = tid & 63, wv = tid >> 6;
    const int lg = lane >> 4, lr = lane & 15;
    const int wrow = (wv >> 1) * 64, wcol = (wv & 1) * 64;

    // A staging: thread owns row ar, k-half ah (32 consecutive f32)
    const int ar = tid >> 1, ah = tid & 1;
    const float* xrow = x + (size_t)ridx[ar] * DIM + ah * 32;
    // B staging: thread owns 4 h-rows (bh4..+3) x 8 k (bkq*8..+8); coalesced f32x4 along h
    const int bkq = tid & 7;
    const int bh4 = ((tid >> 3) & 31) * 4;
    const float* wbase = W1 + (size_t)t * (DIM * HID) + (size_t)bkq * 8 * HID + bh4;

    f32x4 av[8], bv[8];
    f32x4 acc[4][4] = {};

    auto LOADA = [&](int kt) {
        const f32x4* p = (const f32x4*)(xrow + kt * 64);
        #pragma unroll
        for (int e = 0; e < 8; ++e) av[e] = p[e];
    };
    auto LOADB = [&](int kt) {
        const float* p = wbase + (size_t)kt * 64 * HID;
        #pragma unroll
        for (int e = 0; e < 8; ++e) bv[e] = *(const f32x4*)(p + e * HID);
    };
    auto STORE = [&](int buf) {
        short* al = smem + buf * 16384;
        short* bl = al + 8192;
        #pragma unroll
        for (int j = 0; j < 4; ++j) {
            bf16x8 pa = pack8(av[2 * j], av[2 * j + 1]);
            *(bf16x8*)&al[ar * 64 + ((ah * 4 + j) ^ (ar & 7)) * 8] = pa;
        }
        #pragma unroll
        for (int j = 0; j < 4; ++j) {
            const int row = bh4 + j;
            f32x4 c0 = { bv[0][j], bv[1][j], bv[2][j], bv[3][j] };
            f32x4 c1 = { bv[4][j], bv[5][j], bv[6][j], bv[7][j] };
            bf16x8 pb = pack8(c0, c1);
            *(bf16x8*)&bl[row * 64 + (bkq ^ (row & 7)) * 8] = pb;
        }
    };
    auto COMPUTE = [&](int buf) {
        const short* al = smem + buf * 16384;
        const short* bl = al + 8192;
        #pragma unroll
        for (int ks = 0; ks < 2; ++ks) {
            bf16x8 afr[4], bfr[4];
            #pragma unroll
            for (int rf = 0; rf < 4; ++rf) {
                const int row = wrow + rf * 16 + lr;
                afr[rf] = *(const bf16x8*)&al[row * 64 + (((ks << 2) | lg) ^ (row & 7)) * 8];
            }
            #pragma unroll
            for (int cf = 0; cf < 4; ++cf) {
                const int col = wcol + cf * 16 + lr;
                bfr[cf] = *(const bf16x8*)&bl[col * 64 + (((ks << 2) | lg) ^ (col & 7)) * 8];
            }
            #pragma unroll
            for (int rf = 0; rf < 4; ++rf)
                #pragma unroll
                for (int cf = 0; cf < 4; ++cf)
                    acc[rf][cf] = __builtin_amdgcn_mfma_f32_16x16x32_bf16(afr[rf], bfr[cf], acc[rf][cf], 0, 0, 0);
        }
    };

    LOADA(0); LOADB(0);
    #pragma unroll 2
    for (int kt = 0; kt < 16; ++kt) {
        STORE(kt & 1);                       // consumes regs (vmcnt wait), writes buf cur
        __syncthreads();                     // buf cur visible to all
        if (kt < 15) { LOADA(kt + 1); LOADB(kt + 1); }  // prefetch under COMPUTE
        COMPUTE(kt & 1);
    }
    __syncthreads();   // all compute done; smem reused for h tile

    // epilogue: bias + relu, h -> LDS bf16, swizzled [128][256B] rows
    short* hl = smem;
    #pragma unroll
    for (int cf = 0; cf < 4; ++cf) {
        const int col = wcol + cf * 16 + lr;
        const float b1v = b1[t * HID + col];
        #pragma unroll
        for (int rf = 0; rf < 4; ++rf) {
            #pragma unroll
            for (int q = 0; q < 4; ++q) {
                const int row = wrow + rf * 16 + lg * 4 + q;
                float hv = acc[rf][cf][q] + b1v;
                hv = fmaxf(hv, 0.f);
                hl[row * 128 + (((col >> 3) ^ (row & 7)) * 8) + (col & 7)] = f2bf(hv);
            }
        }
    }
    // stage W2^T [16 cls][128 h] bf16 (c padded 10->16 with zeros), swizzled
    short* w2l = smem + 16384;
    for (int idx = tid; idx < 16 * HID; idx += 256) {
        const int c = idx >> 7, h = idx & 127;
        float v = (c < NCLS) ? W2[((size_t)t * HID + h) * NCLS + c] : 0.f;
        w2l[c * 128 + (((h >> 3) ^ (c & 7)) * 8) + (h & 7)] = f2bf(v);
    }
    __syncthreads();

    // second GEMM: [128 x 128] * [128 x 16]; each wave does 32 rows
    f32x4 acc2[2] = {};
    #pragma unroll
    for (int ks = 0; ks < 4; ++ks) {
        bf16x8 bvv = *(const bf16x8*)&w2l[lr * 128 + (((ks << 2) | lg) ^ (lr & 7)) * 8];
        #pragma unroll
        for (int rf = 0; rf < 2; ++rf) {
            const int row = wv * 32 + rf * 16 + lr;
            bf16x8 avv = *(const bf16x8*)&hl[row * 128 + (((ks << 2) | lg) ^ (row & 7)) * 8];
            acc2[rf] = __builtin_amdgcn_mfma_f32_16x16x32_bf16(avv, bvv, acc2[rf], 0, 0, 0);
        }
    }
    if (lr < NCLS) {
        const float b2v = b2[t * NCLS + lr];
        #pragma unroll
        for (int rf = 0; rf < 2; ++rf) {
            #pragma unroll
            for (int q = 0; q < 4; ++q) {
                const int row = wv * 32 + rf * 16 + lg * 4 + q;
                if (row < m) out[(size_t)ridx[row] * NCLS + lr] = acc2[rf][q] + b2v;
            }
        }
    }
}

extern "C" void kernel_launch(void* const* d_in, const int* in_sizes, int n_in,
                              void* d_out, int out_size, void* d_ws, size_t ws_size,
                              hipStream_t stream) {
    (void)in_sizes; (void)n_in; (void)out_size; (void)ws_size;
    const float* x       = (const float*)d_in[0];
    const int*   task_id = (const int*)d_in[1];
    const float* W1      = (const float*)d_in[2];
    const float* b1      = (const float*)d_in[3];
    const float* W2      = (const float*)d_in[4];
    const float* b2      = (const float*)d_in[5];
    float* out = (float*)d_out;
    int* ws = (int*)d_ws;
    // ws (ints): [0,16) cnt | [16,33) off | [33,50) tile-prefix | [50,66) cursors | [256,256+NB) rowIdx
    hipMemsetAsync(ws, 0, 64, stream);
    k_hist<<<NB / 256, 256, 0, stream>>>(task_id, ws);
    k_scan<<<1, 64, 0, stream>>>(ws);
    k_scatter<<<NB / 256, 256, 0, stream>>>(task_id, ws);
    k_main<<<NTILES, 256, 0, stream>>>(x, W1, b1, W2, b2, ws, out);
}